// Round 2
// baseline (384.134 us; speedup 1.0000x reference)
//
#include <hip/hip_runtime.h>
#include <stdint.h>

// Problem sizes (fixed by the reference)
#define BATCH 4096
#define EHC   1024                    // E = H = C
#define DCOMB 3072                    // D = E + H + C
#define NTOT  ((size_t)BATCH * EHC)   // 4M elements per [B, 1024] matrix
#define WGATE ((size_t)EHC * DCOMB)   // 1024*3072 per gate weight
#define WSML  ((size_t)EHC * EHC)     // 1024*1024 (Wh / Wc / Wp)

// GEMM tile config (m97 ladder structure)
#define BM 128
#define BN 128
#define BK 64

typedef __bf16 bf16x8 __attribute__((ext_vector_type(8)));
typedef float  f32x4  __attribute__((ext_vector_type(4)));

__device__ inline unsigned short f2b(float f) {   // round-to-nearest-even bf16
    unsigned int x = __float_as_uint(f);
    unsigned int r = (x + 0x7fffu + ((x >> 16) & 1u)) >> 16;
    return (unsigned short)r;
}
__device__ inline float sigmoid_f(float x) { return 1.0f / (1.0f + __expf(-x)); }
__device__ inline float tanh_f(float x) {
    float xa = fminf(fmaxf(x, -15.0f), 15.0f);   // also kills NaN defensively
    float e = __expf(2.0f * xa);
    return (e - 1.0f) / (e + 1.0f);
}

__device__ inline void load16(const void* g, void* l) {
    __builtin_amdgcn_global_load_lds(
        (const __attribute__((address_space(1))) void*)g,
        (__attribute__((address_space(3))) void*)l, 16, 0, 0);
}

// fp32 -> bf16 conversion, 8 elems/thread, blockIdx.y selects among up to 4 tensors
__global__ __launch_bounds__(256)
void cvt4(const float* __restrict__ s0, const float* __restrict__ s1,
          const float* __restrict__ s2, const float* __restrict__ s3,
          short* __restrict__ dst, size_t tsize)
{
    const int t = blockIdx.y;
    const float* src = (t == 0) ? s0 : (t == 1) ? s1 : (t == 2) ? s2 : s3;
    short* d = dst + (size_t)t * tsize;
    size_t i = ((size_t)blockIdx.x * 256 + threadIdx.x) * 8;
    if (i >= tsize) return;
    float4 a = *(const float4*)(src + i);
    float4 b = *(const float4*)(src + i + 4);
    uint4 v;
    v.x = (unsigned)f2b(a.x) | ((unsigned)f2b(a.y) << 16);
    v.y = (unsigned)f2b(a.z) | ((unsigned)f2b(a.w) << 16);
    v.z = (unsigned)f2b(b.x) | ((unsigned)f2b(b.y) << 16);
    v.w = (unsigned)f2b(b.z) | ((unsigned)f2b(b.w) << 16);
    *(uint4*)(d + i) = v;
}

// Unified fused GEMM:  C[row, col] = sum_k A[row, k] * W[col, k]  (+ epilogue)
// A and W are bf16 (pre-converted in ws). Biases/extra are fp32 (original inputs).
// MODE 1 (gates): K=3072, N=4096 (4 gates x 1024). Epilogue: +bias, sigmoid/tanh,
//                 store bf16 gates to ws.
// MODE 2 (resid): K=2048, N=1024 (hidden||ctx)x(Wh||Wc). Epilogue: +bh+bc+emb(fp32),
//                 store bf16 resid to ws.
// MODE 3 (pred):  K=1024, N=1024. Epilogue: +bp, store fp32 to d_out.
template <int MODE>
__global__ __launch_bounds__(256, 2)
void gemm_fused(const short* __restrict__ A0, const short* __restrict__ A1,
                const short* __restrict__ A2,
                const short* __restrict__ W0, const short* __restrict__ W1,
                const short* __restrict__ W2, const short* __restrict__ W3,
                const float* __restrict__ b0, const float* __restrict__ b1,
                const float* __restrict__ b2, const float* __restrict__ b3,
                const float* __restrict__ extra,
                void* __restrict__ outv)
{
    const int nblk = blockIdx.x;
    const int mblk = blockIdx.y;
    const int tid  = threadIdx.x;
    const int lane = tid & 63;
    const int wave = tid >> 6;
    const int wm = wave >> 1;      // 2x2 wave grid over the 128x128 tile
    const int wn = wave & 1;
    const int l15 = lane & 15;
    const int l4  = lane >> 4;

    __shared__ short As[BM * BK];
    __shared__ short Bs[BN * BK];

    const int K = (MODE == 1) ? DCOMB : (MODE == 2 ? 2048 : 1024);
    const int wstride = (MODE == 1) ? DCOMB : 1024;

    int gate = 0;
    const short* Wsel = W0;
    const float* bsel = b0;
    if (MODE == 1) {
        gate = nblk >> 3;   // 8 n-blocks of 128 per gate
        Wsel = (gate == 0) ? W0 : (gate == 1) ? W1 : (gate == 2) ? W2 : W3;
        bsel = (gate == 0) ? b0 : (gate == 1) ? b1 : (gate == 2) ? b2 : b3;
    }
    const int wrowbase = ((MODE == 1) ? (nblk & 7) : nblk) * BN;

    // Staging: 1024 16B-chunks per tile; thread handles chunks c = j*256+tid.
    // LDS slot = chunk c (dest = wave-uniform base + lane*16, as global_load_lds
    // requires). Global chunk within row r is XOR-swizzled: qg = (c&7) ^ (r&7),
    // so ds_read_b128 fragment reads land 2-way-per-bank (free, m136).
    int aoff[4], woff[4];
#pragma unroll
    for (int j = 0; j < 4; j++) {
        int c  = j * 256 + tid;
        int r  = c >> 3;
        int qg = (c & 7) ^ (r & 7);
        aoff[j] = (mblk * BM + r) * 1024 + qg * 8;
        woff[j] = (wrowbase + r) * wstride + qg * 8;
    }

    // LDS fragment-read offsets (elements), constant over K-tiles.
    // A-frag for 16x16x32: A[m = lane&15][k = (lane>>4)*8 + j]; chunk q = s*4 + l4.
    int a_ld[2][4], b_ld[2][4];
#pragma unroll
    for (int s = 0; s < 2; s++) {
#pragma unroll
        for (int i = 0; i < 4; i++) {
            int q = s * 4 + l4;
            int rowA = wm * 64 + i * 16 + l15;
            a_ld[s][i] = (rowA * 8 + (q ^ (rowA & 7))) * 8;
            int rowB = wn * 64 + i * 16 + l15;
            b_ld[s][i] = (rowB * 8 + (q ^ (rowB & 7))) * 8;
        }
    }

    f32x4 acc[4][4];
#pragma unroll
    for (int i = 0; i < 4; i++)
#pragma unroll
        for (int j = 0; j < 4; j++) acc[i][j] = (f32x4){0.f, 0.f, 0.f, 0.f};

    const int KT = K / BK;
    for (int kt = 0; kt < KT; ++kt) {
        const int k0   = kt * BK;
        const int seg  = (MODE == 3) ? 0 : (k0 >> 10);
        const int acol = k0 & 1023;
        const int wcol = (MODE == 1) ? k0 : acol;
        const short* Aseg = (seg == 0) ? A0 : (seg == 1) ? A1 : A2;
        const short* Wt   = (MODE == 1) ? Wsel : ((seg == 0) ? W0 : W1);

        __syncthreads();   // previous iteration's LDS reads done before overwrite
#pragma unroll
        for (int j = 0; j < 4; j++)
            load16(Aseg + aoff[j] + acol, &As[(j * 256 + tid) * 8]);
#pragma unroll
        for (int j = 0; j < 4; j++)
            load16(Wt + woff[j] + wcol, &Bs[(j * 256 + tid) * 8]);
        __syncthreads();   // compiler drains vmcnt before barrier -> LDS valid

#pragma unroll
        for (int s = 0; s < 2; s++) {
            bf16x8 af[4], bv[4];
#pragma unroll
            for (int i = 0; i < 4; i++) af[i] = *(const bf16x8*)(As + a_ld[s][i]);
#pragma unroll
            for (int i = 0; i < 4; i++) bv[i] = *(const bf16x8*)(Bs + b_ld[s][i]);
#pragma unroll
            for (int mi = 0; mi < 4; mi++)
#pragma unroll
                for (int ni = 0; ni < 4; ni++)
                    acc[mi][ni] = __builtin_amdgcn_mfma_f32_16x16x32_bf16(
                        af[mi], bv[ni], acc[mi][ni], 0, 0, 0);
        }
    }

    // Epilogue. D layout: col = lane&15, row = 4*(lane>>4) + reg  [verified m89/m91].
#pragma unroll
    for (int ni = 0; ni < 4; ni++) {
        const int col = nblk * BN + wn * 64 + ni * 16 + l15;   // global n
        float bias_v;
        if (MODE == 1)      bias_v = bsel[col & 1023];
        else if (MODE == 2) bias_v = b0[col] + b1[col];
        else                bias_v = b0[col];
#pragma unroll
        for (int mi = 0; mi < 4; mi++) {
#pragma unroll
            for (int r = 0; r < 4; r++) {
                const int row = mblk * BM + wm * 64 + mi * 16 + l4 * 4 + r;
                float v = acc[mi][ni][r] + bias_v;
                if (MODE == 1) {
                    v = fminf(fmaxf(v, -30.0f), 30.0f);   // saturate; kills NaN
                    v = (gate < 3) ? sigmoid_f(v) : tanh_f(v);
                    ((short*)outv)[(size_t)gate * NTOT + (size_t)row * 1024 + (col & 1023)]
                        = (short)f2b(v);
                } else if (MODE == 2) {
                    v += extra[(size_t)row * 1024 + col];
                    ((short*)outv)[(size_t)row * 1024 + col] = (short)f2b(v);
                } else {
                    ((float*)outv)[(size_t)row * 1024 + col] = v;
                }
            }
        }
    }
}

// cell = f*pc + i*g ; hidden = o*tanh(cell). Gates bf16 (ws), pc fp32 (input).
// Writes cell fp32 + hidden fp32 (outputs) and hidden bf16 (GEMM2 operand).
__global__ __launch_bounds__(256)
void lstm_cell(const short* __restrict__ gates, const float* __restrict__ pc,
               float* __restrict__ hid_f, float* __restrict__ cell_f,
               short* __restrict__ hid_b)
{
    size_t base = ((size_t)blockIdx.x * 256 + threadIdx.x) * 8;
    if (base >= NTOT) return;
    bf16x8 iv = *(const bf16x8*)(gates + base);
    bf16x8 fv = *(const bf16x8*)(gates + NTOT + base);
    bf16x8 ov = *(const bf16x8*)(gates + 2 * NTOT + base);
    bf16x8 gv = *(const bf16x8*)(gates + 3 * NTOT + base);
    float4 p0 = *(const float4*)(pc + base);
    float4 p1 = *(const float4*)(pc + base + 4);
    float pv[8] = {p0.x, p0.y, p0.z, p0.w, p1.x, p1.y, p1.z, p1.w};
    float cf[8], hf[8];
    uint4 hb;
    unsigned hbp[4];
#pragma unroll
    for (int j = 0; j < 8; j++) {
        float c = (float)fv[j] * pv[j] + (float)iv[j] * (float)gv[j];
        float h = (float)ov[j] * tanh_f(c);
        cf[j] = c; hf[j] = h;
    }
#pragma unroll
    for (int j = 0; j < 4; j++)
        hbp[j] = (unsigned)f2b(hf[2 * j]) | ((unsigned)f2b(hf[2 * j + 1]) << 16);
    hb.x = hbp[0]; hb.y = hbp[1]; hb.z = hbp[2]; hb.w = hbp[3];
    *(float4*)(cell_f + base)     = (float4){cf[0], cf[1], cf[2], cf[3]};
    *(float4*)(cell_f + base + 4) = (float4){cf[4], cf[5], cf[6], cf[7]};
    *(float4*)(hid_f + base)      = (float4){hf[0], hf[1], hf[2], hf[3]};
    *(float4*)(hid_f + base + 4)  = (float4){hf[4], hf[5], hf[6], hf[7]};
    *(uint4*)(hid_b + base) = hb;
}

extern "C" void kernel_launch(void* const* d_in, const int* in_sizes, int n_in,
                              void* d_out, int out_size, void* d_ws, size_t ws_size,
                              hipStream_t stream)
{
    const float* emb  = (const float*)d_in[0];
    const float* hid  = (const float*)d_in[1];
    const float* pcel = (const float*)d_in[2];
    const float* ctx  = (const float*)d_in[3];
    const float* Wi = (const float*)d_in[4];   const float* bi = (const float*)d_in[5];
    const float* Wf = (const float*)d_in[6];   const float* bf_ = (const float*)d_in[7];
    const float* Wo = (const float*)d_in[8];   const float* bo = (const float*)d_in[9];
    const float* Wg = (const float*)d_in[10];  const float* bg = (const float*)d_in[11];
    const float* Wc = (const float*)d_in[12];  const float* bc = (const float*)d_in[13];
    const float* Wh = (const float*)d_in[14];  const float* bh = (const float*)d_in[15];
    const float* Wp = (const float*)d_in[16];  const float* bp = (const float*)d_in[17];

    float* out      = (float*)d_out;
    float* pred     = out;                       // [B,E] fp32
    float* hidden_o = out + NTOT;                // [B,H] fp32
    float* cell_o   = out + 2 * NTOT;            // [B,H] fp32

    // ws layout (bf16 shorts)
    short* ws = (short*)d_ws;
    short* w_emb  = ws;                          // 3 x NTOT activations
    short* w_hid  = ws + NTOT;
    short* w_ctx  = ws + 2 * NTOT;
    short* w_Wg4  = ws + 3 * NTOT;               // 4 x WGATE (Wi,Wf,Wo,Wg)
    short* w_Wh   = w_Wg4 + 4 * WGATE;
    short* w_Wc   = w_Wh + WSML;
    short* w_Wp   = w_Wc + WSML;
    short* w_gat  = w_Wp + WSML;                 // 4 x NTOT activated gates
    short* w_hidb = w_gat + 4 * NTOT;            // new hidden, bf16
    short* w_res  = w_hidb + NTOT;               // resid, bf16

    dim3 blk(256, 1, 1);
    const short* np16 = nullptr;
    const float* npf  = nullptr;

    // 0) fp32 -> bf16 conversions (3 launches)
    hipLaunchKernelGGL(cvt4, dim3((unsigned)(NTOT / 2048), 3), blk, 0, stream,
                       emb, hid, ctx, npf, w_emb, NTOT);
    hipLaunchKernelGGL(cvt4, dim3((unsigned)(WGATE / 2048), 4), blk, 0, stream,
                       Wi, Wf, Wo, Wg, w_Wg4, WGATE);
    hipLaunchKernelGGL(cvt4, dim3((unsigned)(WSML / 2048), 3), blk, 0, stream,
                       Wh, Wc, Wp, npf, w_Wh, WSML);

    // 1) gates GEMM (N=4096 = 4 gates x 1024, K=3072), fused bias+activation
    hipLaunchKernelGGL((gemm_fused<1>), dim3(32, 32), blk, 0, stream,
                       w_emb, w_hid, w_ctx,
                       w_Wg4, w_Wg4 + WGATE, w_Wg4 + 2 * WGATE, w_Wg4 + 3 * WGATE,
                       bi, bf_, bo, bg, npf, (void*)w_gat);
    // 2) cell / hidden elementwise
    hipLaunchKernelGGL(lstm_cell, dim3((unsigned)(NTOT / 8 / 256)), blk, 0, stream,
                       w_gat, pcel, hidden_o, cell_o, w_hidb);
    // 3) resid GEMM: K=2048 (hidden||ctx) x (Wh||Wc), + bh + bc + emb(fp32)
    hipLaunchKernelGGL((gemm_fused<2>), dim3(8, 32), blk, 0, stream,
                       w_hidb, w_ctx, np16, w_Wh, w_Wc, np16, np16,
                       bh, bc, npf, npf, emb, (void*)w_res);
    // 4) prediction GEMM: resid x Wp^T + bp -> fp32 out
    hipLaunchKernelGGL((gemm_fused<3>), dim3(8, 32), blk, 0, stream,
                       w_res, np16, np16, w_Wp, np16, np16, np16,
                       bp, npf, npf, npf, npf, (void*)pred);
}

// Round 3
// 348.777 us; speedup vs baseline: 1.1014x; 1.1014x over previous
//
#include <hip/hip_runtime.h>
#include <stdint.h>

// Problem sizes (fixed by the reference)
#define BATCH 4096
#define EHC   1024                    // E = H = C
#define DCOMB 3072                    // D = E + H + C
#define NTOT  ((size_t)BATCH * EHC)   // 4M elements per [B, 1024] matrix
#define WGATE ((size_t)EHC * DCOMB)   // 1024*3072 per gate weight
#define WSML  ((size_t)EHC * EHC)     // 1024*1024 (Wh / Wc / Wp)

// GEMM tile config (m97 ladder structure). BM fixed; BN per mode.
#define BM 128
#define BK 64

typedef __bf16 bf16x8 __attribute__((ext_vector_type(8)));
typedef float  f32x4  __attribute__((ext_vector_type(4)));

__device__ inline unsigned short f2b(float f) {   // round-to-nearest-even bf16
    unsigned int x = __float_as_uint(f);
    unsigned int r = (x + 0x7fffu + ((x >> 16) & 1u)) >> 16;
    return (unsigned short)r;
}
__device__ inline float sigmoid_f(float x) { return 1.0f / (1.0f + __expf(-x)); }
__device__ inline float tanh_f(float x) {
    float xa = fminf(fmaxf(x, -15.0f), 15.0f);   // also kills NaN defensively
    float e = __expf(2.0f * xa);
    return (e - 1.0f) / (e + 1.0f);
}

__device__ inline void load16(const void* g, void* l) {
    __builtin_amdgcn_global_load_lds(
        (const __attribute__((address_space(1))) void*)g,
        (__attribute__((address_space(3))) void*)l, 16, 0, 0);
}

// Single fused fp32->bf16 conversion over the flat concatenation
//   [emb | hid | ctx | Wi | Wf | Wo | Wg | Wh | Wc | Wp]  ->  ws (contiguous).
// All segment sizes are multiples of 2048 elems (one block's work), so a block
// maps to exactly one segment; segment resolved by a uniform select chain.
__global__ __launch_bounds__(256)
void cvt_all(const float* __restrict__ s0, const float* __restrict__ s1,
             const float* __restrict__ s2, const float* __restrict__ s3,
             const float* __restrict__ s4, const float* __restrict__ s5,
             const float* __restrict__ s6, const float* __restrict__ s7,
             const float* __restrict__ s8, const float* __restrict__ s9,
             short* __restrict__ dst)
{
    // segment starts in block units (2048 elems/block)
    const unsigned b = blockIdx.x;
    const float* src = s0; unsigned st = 0;
    if (b >= 2048)  { src = s1; st = 2048;  }
    if (b >= 4096)  { src = s2; st = 4096;  }
    if (b >= 6144)  { src = s3; st = 6144;  }
    if (b >= 7680)  { src = s4; st = 7680;  }
    if (b >= 9216)  { src = s5; st = 9216;  }
    if (b >= 10752) { src = s6; st = 10752; }
    if (b >= 12288) { src = s7; st = 12288; }
    if (b >= 12800) { src = s8; st = 12800; }
    if (b >= 13312) { src = s9; st = 13312; }
    size_t soff = ((size_t)(b - st) * 2048) + (size_t)threadIdx.x * 8;
    size_t doff = ((size_t)b * 2048) + (size_t)threadIdx.x * 8;
    float4 a = *(const float4*)(src + soff);
    float4 c = *(const float4*)(src + soff + 4);
    uint4 v;
    v.x = (unsigned)f2b(a.x) | ((unsigned)f2b(a.y) << 16);
    v.y = (unsigned)f2b(a.z) | ((unsigned)f2b(a.w) << 16);
    v.z = (unsigned)f2b(c.x) | ((unsigned)f2b(c.y) << 16);
    v.w = (unsigned)f2b(c.z) | ((unsigned)f2b(c.w) << 16);
    *(uint4*)(dst + doff) = v;
}

// Unified fused GEMM:  C[row, col] = sum_k A[row, k] * W[col, k]  (+ epilogue)
// A and W are bf16 (pre-converted in ws). Biases/extra are fp32 (original inputs).
// MODE 1 (gates): K=3072, N=4096 (4 gates x 1024), BN=128. Epilogue: +bias,
//                 sigmoid/tanh, store bf16 gates to ws.
// MODE 2 (resid): K=2048, N=1024, BN=64 (512 blocks -> 2/CU). Epilogue:
//                 +bh+bc+emb(fp32), store bf16 resid to ws.
// MODE 3 (pred):  K=1024, N=1024, BN=64. Epilogue: +bp, store fp32 to d_out.
template <int MODE>
__global__ __launch_bounds__(256, 2)
void gemm_fused(const short* __restrict__ A0, const short* __restrict__ A1,
                const short* __restrict__ A2,
                const short* __restrict__ W0, const short* __restrict__ W1,
                const short* __restrict__ W2, const short* __restrict__ W3,
                const float* __restrict__ b0, const float* __restrict__ b1,
                const float* __restrict__ b2, const float* __restrict__ b3,
                const float* __restrict__ extra,
                void* __restrict__ outv)
{
    constexpr int BNT = (MODE == 1) ? 128 : 64;  // n-tile
    constexpr int NI  = BNT / 32;                // per-wave n-accs AND B-staging iters
    constexpr int WNW = BNT / 2;                 // wave n-region width

    const int nblk = blockIdx.x;
    const int mblk = blockIdx.y;
    const int tid  = threadIdx.x;
    const int lane = tid & 63;
    const int wave = tid >> 6;
    const int wm = wave >> 1;      // 2x2 wave grid over the BM x BNT tile
    const int wn = wave & 1;
    const int l15 = lane & 15;
    const int l4  = lane >> 4;

    __shared__ short As[BM * BK];
    __shared__ short Bs[BNT * BK];

    const int K = (MODE == 1) ? DCOMB : (MODE == 2 ? 2048 : 1024);
    const int wstride = (MODE == 1) ? DCOMB : 1024;

    int gate = 0;
    const short* Wsel = W0;
    const float* bsel = b0;
    if (MODE == 1) {
        gate = nblk >> 3;   // 8 n-blocks of 128 per gate
        Wsel = (gate == 0) ? W0 : (gate == 1) ? W1 : (gate == 2) ? W2 : W3;
        bsel = (gate == 0) ? b0 : (gate == 1) ? b1 : (gate == 2) ? b2 : b3;
    }
    const int wrowbase = ((MODE == 1) ? (nblk & 7) : nblk) * BNT;

    // Staging: 16B chunks; thread handles chunks c = j*256+tid. LDS slot = chunk c
    // (dest = wave-uniform base + lane*16, as global_load_lds requires). Global
    // chunk within row r is XOR-swizzled: qg = (c&7) ^ (r&7), so ds_read_b128
    // fragment reads land 2-way-per-bank (free, m136).
    int aoff[4], woff[NI];
#pragma unroll
    for (int j = 0; j < 4; j++) {
        int c  = j * 256 + tid;
        int r  = c >> 3;
        int qg = (c & 7) ^ (r & 7);
        aoff[j] = (mblk * BM + r) * 1024 + qg * 8;
    }
#pragma unroll
    for (int j = 0; j < NI; j++) {
        int c  = j * 256 + tid;
        int r  = c >> 3;
        int qg = (c & 7) ^ (r & 7);
        woff[j] = (wrowbase + r) * wstride + qg * 8;
    }

    // LDS fragment-read offsets (elements), constant over K-tiles.
    // A-frag for 16x16x32: A[m = lane&15][k = (lane>>4)*8 + j]; chunk q = s*4 + l4.
    int a_ld[2][4], b_ld[2][NI];
#pragma unroll
    for (int s = 0; s < 2; s++) {
#pragma unroll
        for (int i = 0; i < 4; i++) {
            int q = s * 4 + l4;
            int rowA = wm * 64 + i * 16 + l15;
            a_ld[s][i] = (rowA * 8 + (q ^ (rowA & 7))) * 8;
        }
#pragma unroll
        for (int i = 0; i < NI; i++) {
            int q = s * 4 + l4;
            int rowB = wn * WNW + i * 16 + l15;
            b_ld[s][i] = (rowB * 8 + (q ^ (rowB & 7))) * 8;
        }
    }

    f32x4 acc[4][NI];
#pragma unroll
    for (int i = 0; i < 4; i++)
#pragma unroll
        for (int j = 0; j < NI; j++) acc[i][j] = (f32x4){0.f, 0.f, 0.f, 0.f};

    const int KT = K / BK;
    for (int kt = 0; kt < KT; ++kt) {
        const int k0   = kt * BK;
        const int seg  = (MODE == 3) ? 0 : (k0 >> 10);
        const int acol = k0 & 1023;
        const int wcol = (MODE == 1) ? k0 : acol;
        const short* Aseg = (seg == 0) ? A0 : (seg == 1) ? A1 : A2;
        const short* Wt   = (MODE == 1) ? Wsel : ((seg == 0) ? W0 : W1);

        __syncthreads();   // previous iteration's LDS reads done before overwrite
#pragma unroll
        for (int j = 0; j < 4; j++)
            load16(Aseg + aoff[j] + acol, &As[(j * 256 + tid) * 8]);
#pragma unroll
        for (int j = 0; j < NI; j++)
            load16(Wt + woff[j] + wcol, &Bs[(j * 256 + tid) * 8]);
        __syncthreads();   // compiler drains vmcnt before barrier -> LDS valid

#pragma unroll
        for (int s = 0; s < 2; s++) {
            bf16x8 af[4], bv[NI];
#pragma unroll
            for (int i = 0; i < 4; i++) af[i] = *(const bf16x8*)(As + a_ld[s][i]);
#pragma unroll
            for (int i = 0; i < NI; i++) bv[i] = *(const bf16x8*)(Bs + b_ld[s][i]);
#pragma unroll
            for (int mi = 0; mi < 4; mi++)
#pragma unroll
                for (int ni = 0; ni < NI; ni++)
                    acc[mi][ni] = __builtin_amdgcn_mfma_f32_16x16x32_bf16(
                        af[mi], bv[ni], acc[mi][ni], 0, 0, 0);
        }
    }

    // Epilogue. D layout: col = lane&15, row = 4*(lane>>4) + reg  [verified m89/m91].
#pragma unroll
    for (int ni = 0; ni < NI; ni++) {
        const int col = nblk * BNT + wn * WNW + ni * 16 + l15;   // global n
        float bias_v;
        if (MODE == 1)      bias_v = bsel[col & 1023];
        else if (MODE == 2) bias_v = b0[col] + b1[col];
        else                bias_v = b0[col];
#pragma unroll
        for (int mi = 0; mi < 4; mi++) {
#pragma unroll
            for (int r = 0; r < 4; r++) {
                const int row = mblk * BM + wm * 64 + mi * 16 + l4 * 4 + r;
                float v = acc[mi][ni][r] + bias_v;
                if (MODE == 1) {
                    v = fminf(fmaxf(v, -30.0f), 30.0f);   // saturate; kills NaN
                    v = (gate < 3) ? sigmoid_f(v) : tanh_f(v);
                    ((short*)outv)[(size_t)gate * NTOT + (size_t)row * 1024 + (col & 1023)]
                        = (short)f2b(v);
                } else if (MODE == 2) {
                    v += extra[(size_t)row * 1024 + col];
                    ((short*)outv)[(size_t)row * 1024 + col] = (short)f2b(v);
                } else {
                    ((float*)outv)[(size_t)row * 1024 + col] = v;
                }
            }
        }
    }
}

// cell = f*pc + i*g ; hidden = o*tanh(cell). Gates bf16 (ws), pc fp32 (input).
// Writes cell fp32 + hidden fp32 (outputs) and hidden bf16 (GEMM2 operand).
__global__ __launch_bounds__(256)
void lstm_cell(const short* __restrict__ gates, const float* __restrict__ pc,
               float* __restrict__ hid_f, float* __restrict__ cell_f,
               short* __restrict__ hid_b)
{
    size_t base = ((size_t)blockIdx.x * 256 + threadIdx.x) * 8;
    if (base >= NTOT) return;
    bf16x8 iv = *(const bf16x8*)(gates + base);
    bf16x8 fv = *(const bf16x8*)(gates + NTOT + base);
    bf16x8 ov = *(const bf16x8*)(gates + 2 * NTOT + base);
    bf16x8 gv = *(const bf16x8*)(gates + 3 * NTOT + base);
    float4 p0 = *(const float4*)(pc + base);
    float4 p1 = *(const float4*)(pc + base + 4);
    float pv[8] = {p0.x, p0.y, p0.z, p0.w, p1.x, p1.y, p1.z, p1.w};
    float cf[8], hf[8];
    uint4 hb;
    unsigned hbp[4];
#pragma unroll
    for (int j = 0; j < 8; j++) {
        float c = (float)fv[j] * pv[j] + (float)iv[j] * (float)gv[j];
        float h = (float)ov[j] * tanh_f(c);
        cf[j] = c; hf[j] = h;
    }
#pragma unroll
    for (int j = 0; j < 4; j++)
        hbp[j] = (unsigned)f2b(hf[2 * j]) | ((unsigned)f2b(hf[2 * j + 1]) << 16);
    hb.x = hbp[0]; hb.y = hbp[1]; hb.z = hbp[2]; hb.w = hbp[3];
    *(float4*)(cell_f + base)     = (float4){cf[0], cf[1], cf[2], cf[3]};
    *(float4*)(cell_f + base + 4) = (float4){cf[4], cf[5], cf[6], cf[7]};
    *(float4*)(hid_f + base)      = (float4){hf[0], hf[1], hf[2], hf[3]};
    *(float4*)(hid_f + base + 4)  = (float4){hf[4], hf[5], hf[6], hf[7]};
    *(uint4*)(hid_b + base) = hb;
}

extern "C" void kernel_launch(void* const* d_in, const int* in_sizes, int n_in,
                              void* d_out, int out_size, void* d_ws, size_t ws_size,
                              hipStream_t stream)
{
    const float* emb  = (const float*)d_in[0];
    const float* hid  = (const float*)d_in[1];
    const float* pcel = (const float*)d_in[2];
    const float* ctx  = (const float*)d_in[3];
    const float* Wi = (const float*)d_in[4];   const float* bi = (const float*)d_in[5];
    const float* Wf = (const float*)d_in[6];   const float* bf_ = (const float*)d_in[7];
    const float* Wo = (const float*)d_in[8];   const float* bo = (const float*)d_in[9];
    const float* Wg = (const float*)d_in[10];  const float* bg = (const float*)d_in[11];
    const float* Wc = (const float*)d_in[12];  const float* bc = (const float*)d_in[13];
    const float* Wh = (const float*)d_in[14];  const float* bh = (const float*)d_in[15];
    const float* Wp = (const float*)d_in[16];  const float* bp = (const float*)d_in[17];

    float* out      = (float*)d_out;
    float* pred     = out;                       // [B,E] fp32
    float* hidden_o = out + NTOT;                // [B,H] fp32
    float* cell_o   = out + 2 * NTOT;            // [B,H] fp32

    // ws layout (bf16 shorts) — conversion order MUST stay contiguous for cvt_all:
    // [emb | hid | ctx | Wi | Wf | Wo | Wg | Wh | Wc | Wp] then scratch.
    short* ws = (short*)d_ws;
    short* w_emb  = ws;                          // 3 x NTOT activations
    short* w_hid  = ws + NTOT;
    short* w_ctx  = ws + 2 * NTOT;
    short* w_Wg4  = ws + 3 * NTOT;               // 4 x WGATE (Wi,Wf,Wo,Wg)
    short* w_Wh   = w_Wg4 + 4 * WGATE;
    short* w_Wc   = w_Wh + WSML;
    short* w_Wp   = w_Wc + WSML;
    short* w_gat  = w_Wp + WSML;                 // 4 x NTOT activated gates
    short* w_hidb = w_gat + 4 * NTOT;            // new hidden, bf16
    short* w_res  = w_hidb + NTOT;               // resid, bf16

    dim3 blk(256, 1, 1);
    const short* np16 = nullptr;
    const float* npf  = nullptr;

    // 0) one fused fp32->bf16 conversion pass (28.3M elems, 13824 blocks)
    hipLaunchKernelGGL(cvt_all, dim3(13824), blk, 0, stream,
                       emb, hid, ctx, Wi, Wf, Wo, Wg, Wh, Wc, Wp, ws);

    // 1) gates GEMM (N=4096 = 4 gates x 1024, K=3072), fused bias+activation
    hipLaunchKernelGGL((gemm_fused<1>), dim3(32, 32), blk, 0, stream,
                       w_emb, w_hid, w_ctx,
                       w_Wg4, w_Wg4 + WGATE, w_Wg4 + 2 * WGATE, w_Wg4 + 3 * WGATE,
                       bi, bf_, bo, bg, npf, (void*)w_gat);
    // 2) cell / hidden elementwise
    hipLaunchKernelGGL(lstm_cell, dim3((unsigned)(NTOT / 8 / 256)), blk, 0, stream,
                       w_gat, pcel, hidden_o, cell_o, w_hidb);
    // 3) resid GEMM: K=2048 (hidden||ctx) x (Wh||Wc), + bh + bc + emb(fp32), BN=64
    hipLaunchKernelGGL((gemm_fused<2>), dim3(16, 32), blk, 0, stream,
                       w_hidb, w_ctx, np16, w_Wh, w_Wc, np16, np16,
                       bh, bc, npf, npf, emb, (void*)w_res);
    // 4) prediction GEMM: resid x Wp^T + bp -> fp32 out, BN=64
    hipLaunchKernelGGL((gemm_fused<3>), dim3(16, 32), blk, 0, stream,
                       w_res, np16, np16, w_Wp, np16, np16, np16,
                       bp, npf, npf, npf, npf, (void*)pred);
}

// Round 4
// 333.098 us; speedup vs baseline: 1.1532x; 1.0471x over previous
//
#include <hip/hip_runtime.h>
#include <stdint.h>

// Problem sizes (fixed by the reference)
#define BATCH 4096
#define EHC   1024                    // E = H = C
#define DCOMB 3072                    // D = E + H + C
#define NTOT  ((size_t)BATCH * EHC)   // 4M elements per [B, 1024] matrix
#define WGATE ((size_t)EHC * DCOMB)   // 1024*3072 per gate weight
#define WSML  ((size_t)EHC * EHC)     // 1024*1024 (Wh / Wc / Wp)

#define BK 64

typedef __bf16 bf16x8 __attribute__((ext_vector_type(8)));
typedef float  f32x4  __attribute__((ext_vector_type(4)));

__device__ inline unsigned short f2b(float f) {   // round-to-nearest-even bf16
    unsigned int x = __float_as_uint(f);
    unsigned int r = (x + 0x7fffu + ((x >> 16) & 1u)) >> 16;
    return (unsigned short)r;
}
__device__ inline float sigmoid_f(float x) { return 1.0f / (1.0f + __expf(-x)); }
__device__ inline float tanh_f(float x) {
    float xa = fminf(fmaxf(x, -15.0f), 15.0f);   // also kills NaN defensively
    float e = __expf(2.0f * xa);
    return (e - 1.0f) / (e + 1.0f);
}

__device__ inline void load16(const void* g, void* l) {
    __builtin_amdgcn_global_load_lds(
        (const __attribute__((address_space(1))) void*)g,
        (__attribute__((address_space(3))) void*)l, 16, 0, 0);
}

// Single fused fp32->bf16 conversion over the flat concatenation
//   [emb | hid | ctx | Wi | Wf | Wo | Wg | Wh | Wc | Wp]  ->  ws (contiguous).
// All segment sizes are multiples of 2048 elems (one block's work).
__global__ __launch_bounds__(256)
void cvt_all(const float* __restrict__ s0, const float* __restrict__ s1,
             const float* __restrict__ s2, const float* __restrict__ s3,
             const float* __restrict__ s4, const float* __restrict__ s5,
             const float* __restrict__ s6, const float* __restrict__ s7,
             const float* __restrict__ s8, const float* __restrict__ s9,
             short* __restrict__ dst)
{
    const unsigned b = blockIdx.x;
    const float* src = s0; unsigned st = 0;
    if (b >= 2048)  { src = s1; st = 2048;  }
    if (b >= 4096)  { src = s2; st = 4096;  }
    if (b >= 6144)  { src = s3; st = 6144;  }
    if (b >= 7680)  { src = s4; st = 7680;  }
    if (b >= 9216)  { src = s5; st = 9216;  }
    if (b >= 10752) { src = s6; st = 10752; }
    if (b >= 12288) { src = s7; st = 12288; }
    if (b >= 12800) { src = s8; st = 12800; }
    if (b >= 13312) { src = s9; st = 13312; }
    size_t soff = ((size_t)(b - st) * 2048) + (size_t)threadIdx.x * 8;
    size_t doff = ((size_t)b * 2048) + (size_t)threadIdx.x * 8;
    float4 a = *(const float4*)(src + soff);
    float4 c = *(const float4*)(src + soff + 4);
    uint4 v;
    v.x = (unsigned)f2b(a.x) | ((unsigned)f2b(a.y) << 16);
    v.y = (unsigned)f2b(a.z) | ((unsigned)f2b(a.w) << 16);
    v.z = (unsigned)f2b(c.x) | ((unsigned)f2b(c.y) << 16);
    v.w = (unsigned)f2b(c.z) | ((unsigned)f2b(c.w) << 16);
    *(uint4*)(dst + doff) = v;
}

// Unified fused GEMM:  C[row, col] = sum_k A[row, k] * W[col, k]  (+ epilogue)
// MODE 1 (gates+cell, FUSED): BM=128, BN=64 over N=1024, NG=4 weight operands
//   (Wi,Wf,Wo,Wg) sharing one A-tile. K=3072 via segs {emb,hid,ctx}. Epilogue
//   computes i,f,o,g -> cell/hidden in-register; writes cell f32 (outv),
//   hidden f32 (out2), hidden bf16 (out3). extra = previous_cell_state (f32).
// MODE 2 (resid): BM=BN=64, K=2048 segs {hidden,ctx} x {Wh,Wc}.
//   Epilogue: +b0+b1+extra(emb f32); bf16 store to outv.
// MODE 3 (pred):  BM=BN=64, K=1024. Epilogue: +b0; f32 store to outv.
template <int MODE>
__global__ __launch_bounds__(256, 2)
void gemm_fused(const short* __restrict__ A0, const short* __restrict__ A1,
                const short* __restrict__ A2,
                const short* __restrict__ W0, const short* __restrict__ W1,
                const short* __restrict__ W2, const short* __restrict__ W3,
                const float* __restrict__ b0, const float* __restrict__ b1,
                const float* __restrict__ b2, const float* __restrict__ b3,
                const float* __restrict__ extra,
                void* __restrict__ outv, float* __restrict__ out2,
                short* __restrict__ out3)
{
    constexpr int NG  = (MODE == 1) ? 4 : 1;     // parallel B operands (gates)
    constexpr int BMT = (MODE == 1) ? 128 : 64;  // m-tile
    constexpr int BNT = 64;                      // n-tile
    constexpr int MI  = BMT / 32;                // per-wave m-accs
    constexpr int NI  = BNT / 32;                // per-wave n-accs
    constexpr int AI  = BMT / 32;                // A staging iters (BMT*8/256)
    constexpr int BI  = BNT / 32;                // B staging iters per operand
    constexpr int WMH = BMT / 2;                 // wave m-region
    constexpr int BSZ = BNT * BK;                // one B operand in LDS (elems)

    const int nblk = blockIdx.x;
    const int mblk = blockIdx.y;
    const int tid  = threadIdx.x;
    const int lane = tid & 63;
    const int wave = tid >> 6;
    const int wm = wave >> 1;      // 2x2 wave grid over the BMT x BNT tile
    const int wn = wave & 1;
    const int l15 = lane & 15;
    const int l4  = lane >> 4;

    __shared__ short As[BMT * BK];
    __shared__ short Bs[NG * BSZ];

    const int K = (MODE == 1) ? DCOMB : (MODE == 2 ? 2048 : 1024);
    const int wstride = (MODE == 1) ? DCOMB : 1024;
    const int wrowbase = nblk * BNT;

    // Staging: 16B chunks; thread handles chunks c = j*256+tid. LDS slot = chunk c
    // (dest = wave-uniform base + lane*16, as global_load_lds requires). Global
    // chunk within row r is XOR-swizzled: qg = (c&7) ^ (r&7), so ds_read_b128
    // fragment reads land 2-way-per-bank (free, m136).
    int aoff[AI], woff[BI];
#pragma unroll
    for (int j = 0; j < AI; j++) {
        int c  = j * 256 + tid;
        int r  = c >> 3;
        int qg = (c & 7) ^ (r & 7);
        aoff[j] = (mblk * BMT + r) * 1024 + qg * 8;
    }
#pragma unroll
    for (int j = 0; j < BI; j++) {
        int c  = j * 256 + tid;
        int r  = c >> 3;
        int qg = (c & 7) ^ (r & 7);
        woff[j] = (wrowbase + r) * wstride + qg * 8;
    }

    // LDS fragment-read offsets (elements), constant over K-tiles.
    // A-frag for 16x16x32: A[m = lane&15][k = (lane>>4)*8 + j]; chunk q = s*4 + l4.
    int a_ld[2][MI], b_ld[2][NI];
#pragma unroll
    for (int s = 0; s < 2; s++) {
        int q = s * 4 + l4;
#pragma unroll
        for (int i = 0; i < MI; i++) {
            int rowA = wm * WMH + i * 16 + l15;
            a_ld[s][i] = (rowA * 8 + (q ^ (rowA & 7))) * 8;
        }
#pragma unroll
        for (int i = 0; i < NI; i++) {
            int rowB = wn * 32 + i * 16 + l15;
            b_ld[s][i] = (rowB * 8 + (q ^ (rowB & 7))) * 8;
        }
    }

    f32x4 acc[NG][MI][NI];
#pragma unroll
    for (int g = 0; g < NG; g++)
#pragma unroll
        for (int i = 0; i < MI; i++)
#pragma unroll
            for (int j = 0; j < NI; j++) acc[g][i][j] = (f32x4){0.f, 0.f, 0.f, 0.f};

    const int KT = K / BK;
    for (int kt = 0; kt < KT; ++kt) {
        const int k0   = kt * BK;
        const int seg  = (MODE == 3) ? 0 : (k0 >> 10);
        const int acol = k0 & 1023;
        const short* Aseg = (seg == 0) ? A0 : (seg == 1) ? A1 : A2;

        __syncthreads();   // previous iteration's LDS reads done before overwrite
#pragma unroll
        for (int j = 0; j < AI; j++)
            load16(Aseg + aoff[j] + acol, &As[(j * 256 + tid) * 8]);
        if (MODE == 1) {
            const short* Wg4[4] = {W0, W1, W2, W3};
#pragma unroll
            for (int g = 0; g < 4; g++)
#pragma unroll
                for (int j = 0; j < BI; j++)
                    load16(Wg4[g] + woff[j] + k0, &Bs[g * BSZ + (j * 256 + tid) * 8]);
        } else {
            const short* Wt = (seg == 0) ? W0 : W1;
#pragma unroll
            for (int j = 0; j < BI; j++)
                load16(Wt + woff[j] + acol, &Bs[(j * 256 + tid) * 8]);
        }
        __syncthreads();   // compiler drains vmcnt before barrier -> LDS valid

#pragma unroll
        for (int s = 0; s < 2; s++) {
            bf16x8 af[MI];
#pragma unroll
            for (int i = 0; i < MI; i++) af[i] = *(const bf16x8*)(As + a_ld[s][i]);
#pragma unroll
            for (int g = 0; g < NG; g++) {
                bf16x8 bv[NI];
#pragma unroll
                for (int i = 0; i < NI; i++)
                    bv[i] = *(const bf16x8*)(Bs + g * BSZ + b_ld[s][i]);
#pragma unroll
                for (int mi = 0; mi < MI; mi++)
#pragma unroll
                    for (int ni = 0; ni < NI; ni++)
                        acc[g][mi][ni] = __builtin_amdgcn_mfma_f32_16x16x32_bf16(
                            af[mi], bv[ni], acc[g][mi][ni], 0, 0, 0);
            }
        }
    }

    // Epilogue. D layout: col = lane&15, row = 4*(lane>>4) + reg  [verified m89/m91].
#pragma unroll
    for (int ni = 0; ni < NI; ni++) {
        const int col = nblk * BNT + wn * 32 + ni * 16 + l15;
        if (MODE == 1) {
            const float bi_ = b0[col], bf_ = b1[col], bo_ = b2[col], bg_ = b3[col];
#pragma unroll
            for (int mi = 0; mi < MI; mi++) {
#pragma unroll
                for (int r = 0; r < 4; r++) {
                    const size_t row = (size_t)(mblk * BMT + wm * WMH + mi * 16 + l4 * 4 + r);
                    const size_t idx = row * 1024 + col;
                    float ai = fminf(fmaxf(acc[0][mi][ni][r] + bi_, -30.f), 30.f);
                    float af_ = fminf(fmaxf(acc[1][mi][ni][r] + bf_, -30.f), 30.f);
                    float ao = fminf(fmaxf(acc[2][mi][ni][r] + bo_, -30.f), 30.f);
                    float ag = fminf(fmaxf(acc[3][mi][ni][r] + bg_, -30.f), 30.f);
                    float ig = sigmoid_f(ai), fg = sigmoid_f(af_);
                    float og = sigmoid_f(ao), gg = tanh_f(ag);
                    float c = fg * extra[idx] + ig * gg;   // extra = prev cell (f32)
                    float h = og * tanh_f(c);
                    ((float*)outv)[idx] = c;               // cell_state (f32 out)
                    out2[idx] = h;                         // hidden (f32 out)
                    out3[idx] = (short)f2b(h);             // hidden (bf16, GEMM2 A)
                }
            }
        } else {
            float bias_v = (MODE == 2) ? (b0[col] + b1[col]) : b0[col];
#pragma unroll
            for (int mi = 0; mi < MI; mi++) {
#pragma unroll
                for (int r = 0; r < 4; r++) {
                    const size_t row = (size_t)(mblk * BMT + wm * WMH + mi * 16 + l4 * 4 + r);
                    const size_t idx = row * 1024 + col;
                    float v = acc[0][mi][ni][r] + bias_v;
                    if (MODE == 2) {
                        v += extra[idx];                   // + emb (f32)
                        ((short*)outv)[idx] = (short)f2b(v);
                    } else {
                        ((float*)outv)[idx] = v;
                    }
                }
            }
        }
    }
}

extern "C" void kernel_launch(void* const* d_in, const int* in_sizes, int n_in,
                              void* d_out, int out_size, void* d_ws, size_t ws_size,
                              hipStream_t stream)
{
    const float* emb  = (const float*)d_in[0];
    const float* hid  = (const float*)d_in[1];
    const float* pcel = (const float*)d_in[2];
    const float* ctx  = (const float*)d_in[3];
    const float* Wi = (const float*)d_in[4];   const float* bi = (const float*)d_in[5];
    const float* Wf = (const float*)d_in[6];   const float* bf_ = (const float*)d_in[7];
    const float* Wo = (const float*)d_in[8];   const float* bo = (const float*)d_in[9];
    const float* Wg = (const float*)d_in[10];  const float* bg = (const float*)d_in[11];
    const float* Wc = (const float*)d_in[12];  const float* bc = (const float*)d_in[13];
    const float* Wh = (const float*)d_in[14];  const float* bh = (const float*)d_in[15];
    const float* Wp = (const float*)d_in[16];  const float* bp = (const float*)d_in[17];

    float* out      = (float*)d_out;
    float* pred     = out;                       // [B,E] fp32
    float* hidden_o = out + NTOT;                // [B,H] fp32
    float* cell_o   = out + 2 * NTOT;            // [B,H] fp32

    // ws layout (bf16 shorts) — conversion order MUST stay contiguous for cvt_all:
    // [emb | hid | ctx | Wi | Wf | Wo | Wg | Wh | Wc | Wp] then scratch.
    short* ws = (short*)d_ws;
    short* w_emb  = ws;                          // 3 x NTOT activations
    short* w_hid  = ws + NTOT;
    short* w_ctx  = ws + 2 * NTOT;
    short* w_Wg4  = ws + 3 * NTOT;               // 4 x WGATE (Wi,Wf,Wo,Wg)
    short* w_Wh   = w_Wg4 + 4 * WGATE;
    short* w_Wc   = w_Wh + WSML;
    short* w_Wp   = w_Wc + WSML;
    short* w_hidb = w_Wp + WSML;                 // new hidden, bf16
    short* w_res  = w_hidb + NTOT;               // resid, bf16

    dim3 blk(256, 1, 1);
    const short* np16 = nullptr;
    const float* npf  = nullptr;

    // 0) one fused fp32->bf16 conversion pass (28.3M elems, 13824 blocks)
    hipLaunchKernelGGL(cvt_all, dim3(13824), blk, 0, stream,
                       emb, hid, ctx, Wi, Wf, Wo, Wg, Wh, Wc, Wp, ws);

    // 1) fused gates GEMM + cell/hidden epilogue (NG=4, 128x64 tiles, N=1024)
    hipLaunchKernelGGL((gemm_fused<1>), dim3(16, 32), blk, 0, stream,
                       w_emb, w_hid, w_ctx,
                       w_Wg4, w_Wg4 + WGATE, w_Wg4 + 2 * WGATE, w_Wg4 + 3 * WGATE,
                       bi, bf_, bo, bg, pcel,
                       (void*)cell_o, hidden_o, w_hidb);
    // 2) resid GEMM: K=2048 (hidden||ctx) x (Wh||Wc), + bh + bc + emb(fp32)
    hipLaunchKernelGGL((gemm_fused<2>), dim3(16, 64), blk, 0, stream,
                       w_hidb, w_ctx, np16, w_Wh, w_Wc, np16, np16,
                       bh, bc, npf, npf, emb, (void*)w_res, (float*)nullptr, (short*)nullptr);
    // 3) prediction GEMM: resid x Wp^T + bp -> fp32 out
    hipLaunchKernelGGL((gemm_fused<3>), dim3(16, 64), blk, 0, stream,
                       w_res, np16, np16, w_Wp, np16, np16, np16,
                       bp, npf, npf, npf, npf, (void*)pred, (float*)nullptr, (short*)nullptr);
}